// Round 8
// baseline (301.440 us; speedup 1.0000x reference)
//
#include <hip/hip_runtime.h>
#include <hip/hip_bf16.h>

// B=2, T=2048, C=1024, H=16, HD=64, R=32, LORA_SCALE=0.5. f32 I/O, bf16 MFMA.
//   convert_all: all params+x -> bf16 ws
//   t1 = 0.5 * x @ la_attn^T                       (lora_t)
//   qk | vt = x @ w_attn^T + b_attn + t1 @ lb_attn^T  (gemm_lora; V transposed,
//             q columns pre-scaled by 0.125*log2(e) for exp2-softmax)
//   y = causal flash attention (no-max softmax, ones-MFMA row sums, S^T form)
//   t2 = 0.5 * y @ la_proj^T                       (lora_t)
//   out = y @ w_proj^T + b_proj + t2 @ lb_proj^T   (gemm_lora, f32 out)

typedef __attribute__((ext_vector_type(8))) short short8;   // 8 x bf16
typedef __attribute__((ext_vector_type(4))) float float4v;  // MFMA accum

#define QSCALE 0.18033688011112292f  // 0.125 * log2(e)

static __device__ __forceinline__ float b2f(ushort u) {
  union { uint i; float f; } v; v.i = ((uint)u) << 16; return v.f;
}
static __device__ __forceinline__ ushort f2b(float f) {
  union { float f; uint i; } v; v.f = f;
  uint i = v.i + 0x7fffu + ((v.i >> 16) & 1u);  // RNE
  return (ushort)(i >> 16);
}
static __device__ __forceinline__ float4v zero4() {
  float4v z = {0.f, 0.f, 0.f, 0.f}; return z;
}
// async global->LDS; HW dest = wave-uniform LDS base + lane*16
static __device__ __forceinline__ void glld16(const void* g, void* l) {
  __builtin_amdgcn_global_load_lds((const __attribute__((address_space(1))) void*)g,
                                   (__attribute__((address_space(3))) void*)l,
                                   16, 0, 0);
}

// ---------------- merged f32 -> bf16 conversion (7 segments, float4 chunks)
__global__ __launch_bounds__(256) void convert_all(
    const float* __restrict__ x, const float* __restrict__ wa,
    const float* __restrict__ la, const float* __restrict__ lb,
    const float* __restrict__ wp, const float* __restrict__ lp,
    const float* __restrict__ lq,
    ushort* __restrict__ xb, ushort* __restrict__ wab, ushort* __restrict__ lab,
    ushort* __restrict__ lbb, ushort* __restrict__ wpb, ushort* __restrict__ lpb,
    ushort* __restrict__ lqb) {
  const int stride = gridDim.x * blockDim.x;
  for (int i = blockIdx.x * blockDim.x + threadIdx.x; i < 2146304; i += stride) {
    const float* s; ushort* d; int off;
    if (i < 1048576)      { s = x;  d = xb;  off = i; }
    else if (i < 1835008) { s = wa; d = wab; off = i - 1048576; }
    else if (i < 1843200) { s = la; d = lab; off = i - 1835008; }
    else if (i < 1867776) { s = lb; d = lbb; off = i - 1843200; }
    else if (i < 2129920) { s = wp; d = wpb; off = i - 1867776; }
    else if (i < 2138112) { s = lp; d = lpb; off = i - 2129920; }
    else                  { s = lq; d = lqb; off = i - 2138112; }
    float4 v = ((const float4*)s)[off];
    union { ushort u[4]; uint2 p; } o;
    o.u[0] = f2b(v.x); o.u[1] = f2b(v.y); o.u[2] = f2b(v.z); o.u[3] = f2b(v.w);
    ((uint2*)d)[off] = o.p;
  }
}

// ---------------- LoRA down: T[m][r] = 0.5 * sum_k X[m][k]*La[r][k]
__global__ __launch_bounds__(256) void lora_t(
    const ushort* __restrict__ X, const ushort* __restrict__ La,
    ushort* __restrict__ T) {
  const int tid = threadIdx.x;
  const int m = blockIdx.x * 8 + (tid >> 5);
  const int r = tid & 31;
  const uint4* xr = (const uint4*)(X + (size_t)m * 1024);
  const uint4* lr = (const uint4*)(La + (size_t)r * 1024);
  float s = 0.f;
#pragma unroll 4
  for (int kk = 0; kk < 128; ++kk) {
    uint4 xv = xr[kk], lv = lr[kk];
    s += b2f((ushort)xv.x) * b2f((ushort)lv.x) + b2f((ushort)(xv.x >> 16)) * b2f((ushort)(lv.x >> 16));
    s += b2f((ushort)xv.y) * b2f((ushort)lv.y) + b2f((ushort)(xv.y >> 16)) * b2f((ushort)(lv.y >> 16));
    s += b2f((ushort)xv.z) * b2f((ushort)lv.z) + b2f((ushort)(xv.z >> 16)) * b2f((ushort)(lv.z >> 16));
    s += b2f((ushort)xv.w) * b2f((ushort)lv.w) + b2f((ushort)(xv.w >> 16)) * b2f((ushort)(lv.w >> 16));
  }
  T[(size_t)m * 32 + r] = f2b(0.5f * s);
}

// ---------------- GEMM + LoRA tail. 128x128 tile, BK=32, double-buffered LDS
// with prefetch-during-compute. XCD m-band swizzle. LoRA tail = iteration KT.
// VSPLIT: q cols (n<1024) scaled by QSCALE; v cols (n>=2048) written transposed.
template <bool OUTF32, bool VSPLIT, int NBX>
__global__ __launch_bounds__(256) void gemm_lora(
    const ushort* __restrict__ A, const ushort* __restrict__ W,
    const float* __restrict__ bias,
    const ushort* __restrict__ T1, const ushort* __restrict__ Lb,
    void* __restrict__ outv, ushort* __restrict__ vt, int K, int ldo) {
  __shared__ __attribute__((aligned(16))) ushort As[2][128 * 32];  // 8 KB each
  __shared__ __attribute__((aligned(16))) ushort Ws[2][128 * 32];
  const int tid = threadIdx.x;
  const int lane = tid & 63, wv = tid >> 6;
  const int l15 = lane & 15, quad = lane >> 4;
  const int L = blockIdx.x;
  const int x8 = L & 7, q = L >> 3;
  const int bx = q % NBX;
  const int by = x8 * 4 + q / NBX;   // nby = 32 always here
  const int m0 = by * 128, n0 = bx * 128;
  const int wm = (wv >> 1) * 64, wn = (wv & 1) * 64;
  const int r4 = lane >> 2, c4 = (lane & 3) * 8;  // 16 rows x 64B per glld16
  const int KT = K >> 5;

  float4v acc[4][4];
#pragma unroll
  for (int i = 0; i < 4; i++)
#pragma unroll
    for (int j = 0; j < 4; j++) acc[i][j] = zero4();

  auto stage = [&](int t, int buf) {
    const ushort* sA; const ushort* sW; int ld, k0;
    if (t < KT) { sA = A; sW = W; ld = K; k0 = t * 32; }
    else        { sA = T1; sW = Lb; ld = 32; k0 = 0; }
#pragma unroll
    for (int u = 0; u < 2; ++u) {
      int R = wv * 32 + u * 16;
      glld16(sA + (size_t)(m0 + R + r4) * ld + k0 + c4, &As[buf][R * 32]);
      glld16(sW + (size_t)(n0 + R + r4) * ld + k0 + c4, &Ws[buf][R * 32]);
    }
  };

  stage(0, 0);
  for (int t = 0; t <= KT; ++t) {
    __syncthreads();                     // drains stage(t) vmcnt + prev reads
    if (t < KT) stage(t + 1, (t + 1) & 1);
    const int b = t & 1;
    short8 af[4], wf[4];
#pragma unroll
    for (int i = 0; i < 4; i++)
      af[i] = *(const short8*)&As[b][(wm + i * 16 + l15) * 32 + quad * 8];
#pragma unroll
    for (int j = 0; j < 4; j++)
      wf[j] = *(const short8*)&Ws[b][(wn + j * 16 + l15) * 32 + quad * 8];
#pragma unroll
    for (int i = 0; i < 4; i++)
#pragma unroll
      for (int j = 0; j < 4; j++)
        acc[i][j] = __builtin_amdgcn_mfma_f32_16x16x32_bf16(af[i], wf[j], acc[i][j], 0, 0, 0);
  }

  const float qsc = (VSPLIT && n0 < 1024) ? QSCALE : 1.0f;
  // epilogue: C/D row = quad*4 + r, col = l15
#pragma unroll
  for (int i = 0; i < 4; i++) {
    int gm = m0 + wm + i * 16 + quad * 4;
#pragma unroll
    for (int j = 0; j < 4; j++) {
      int gn = n0 + wn + j * 16 + l15;
      float bb = bias[gn];
      if (VSPLIT && n0 >= 2048) {
        int vc = gn - 2048;                       // 0..1023 within (h,d)
        int bb2 = gm >> 11, t = gm & 2047;
        ushort u0 = f2b(acc[i][j][0] + bb), u1 = f2b(acc[i][j][1] + bb);
        ushort u2 = f2b(acc[i][j][2] + bb), u3 = f2b(acc[i][j][3] + bb);
        uint2 pk; pk.x = (uint)u0 | ((uint)u1 << 16); pk.y = (uint)u2 | ((uint)u3 << 16);
        *(uint2*)(vt + ((size_t)bb2 * 1024 + vc) * 2048 + t) = pk;
      } else {
#pragma unroll
        for (int r = 0; r < 4; r++) {
          float val = (acc[i][j][r] + bb) * qsc;
          if (OUTF32) ((float*)outv)[(size_t)(gm + r) * ldo + gn] = val;
          else        ((ushort*)outv)[(size_t)(gm + r) * ldo + gn] = f2b(val);
        }
      }
    }
  }
}

// ---------------- Causal flash attention, S^T form, 64 q-rows/wave.
// grid 256 = 1 block/CU, 256 thr (4 waves). Block L: bh = (L&7)*4+((L>>3)&3)
// (XCD-local K/V), pair g = L>>5: waves 0-1 -> q-tile 15-g (heavy, 64 rows
// each), waves 2-3 -> q-tile g (light), sharing K/V staging.
// S^T = K Q^T via operand-swapped MFMA: C row = key = quad*4+r, col = q = l15
// -> P written as packed b64 (4 consecutive keys per q-row), loop-invariant
// addresses, optimal bank spread. All LDS tiles col-rotated by 8*(row%8)
// at glld time; logical col k read at (k - 8*(row%8)) & 63.
// LDS: Ks 16KB + Vts 16KB + Ps (4 waves x 64x64, Q staging too) 32KB = 64KB.
__global__ __launch_bounds__(256) void flash_attn(
    const ushort* __restrict__ qk, const ushort* __restrict__ vt,
    ushort* __restrict__ y) {
  __shared__ __attribute__((aligned(16))) ushort Ks[2][64 * 64];
  __shared__ __attribute__((aligned(16))) ushort Vts[2][64 * 64];
  __shared__ __attribute__((aligned(16))) ushort Ps[4 * 64 * 64];
  const int tid = threadIdx.x;
  const int lane = tid & 63, wv = tid >> 6;
  const int l15 = lane & 15, quad = lane >> 4;
  const int L = blockIdx.x;
  const int bh = (L & 7) * 4 + ((L >> 3) & 3);
  const int g = L >> 5;
  const int b = bh >> 4, h = bh & 15;
  const int qbH = 15 - g, qbL = g;
  const int qtile = (wv < 2) ? qbH : qbL;
  const int qrow0 = qtile * 128 + (wv & 1) * 64;   // this wave's 64 q-rows
  const int myLast = 2 * qtile + (wv & 1);         // last kb with any unmasked key
  const int lastH = 2 * qbH + 1;                   // block loop bound
  const ushort* qbase = qk + (size_t)b * 2048 * 2048 + h * 64;
  const ushort* kbase = qk + (size_t)b * 2048 * 2048 + 1024 + h * 64;
  const ushort* vbase = vt + ((size_t)b * 1024 + h * 64) * 2048;
  const int r8 = lane >> 3, c8 = (lane & 7) * 8;
  const int rotc = (c8 + 8 * r8) & 63;             // glld write rotation
  const int m8 = l15 & 7;
  const int colk0 = (quad * 8 + 64 - 8 * m8) & 63; // 8-chunk read col, kt=0
  const int colk1 = (colk0 + 32) & 63;             // kt=1
  int wcol[4];                                     // P b64 write cols (per jk)
#pragma unroll
  for (int jk = 0; jk < 4; ++jk) wcol[jk] = (jk * 16 + quad * 4 + 64 - 8 * m8) & 63;
  const int pB = wv * 4096;                        // wave-private Ps (64x64)

  // stage this wave's 64 Q rows into its Ps region (rotated)
#pragma unroll
  for (int u = 0; u < 8; ++u)
    glld16(qbase + (size_t)(qrow0 + u * 8 + r8) * 2048 + rotc, &Ps[pB + u * 8 * 64]);
  // K/V tile 0 (cooperative: wave wv stages rows wv*16..+15)
#pragma unroll
  for (int u = 0; u < 2; ++u) {
    int R = wv * 16 + u * 8;
    glld16(kbase + (size_t)(R + r8) * 2048 + rotc, &Ks[0][R * 64]);
    glld16(vbase + (size_t)(R + r8) * 2048 + rotc, &Vts[0][R * 64]);
  }
  __syncthreads();
  short8 aq[4][2];
#pragma unroll
  for (int iq = 0; iq < 4; ++iq) {
    aq[iq][0] = *(const short8*)&Ps[pB + (iq * 16 + l15) * 64 + colk0];
    aq[iq][1] = *(const short8*)&Ps[pB + (iq * 16 + l15) * 64 + colk1];
  }
  // Ps region is wave-private; safe to reuse for P without a barrier.

  short8 ones;
#pragma unroll
  for (int e = 0; e < 8; e++) ones[e] = (short)0x3F80;  // bf16 1.0

  float4v acc[4][4];   // [iq][d-tile]
  float4v lacc[4];     // [iq]
#pragma unroll
  for (int i = 0; i < 4; ++i) {
    lacc[i] = zero4();
#pragma unroll
    for (int jt = 0; jt < 4; jt++) acc[i][jt] = zero4();
  }

  for (int kb = 0; kb <= lastH; ++kb) {
    const int cur = kb & 1;
    if (kb < lastH) {
      const int nb = cur ^ 1;
#pragma unroll
      for (int u = 0; u < 2; ++u) {
        int R = wv * 16 + u * 8;
        glld16(kbase + (size_t)((kb + 1) * 64 + R + r8) * 2048 + rotc, &Ks[nb][R * 64]);
        glld16(vbase + (size_t)(R + r8) * 2048 + (kb + 1) * 64 + rotc, &Vts[nb][R * 64]);
      }
    }
    if (kb <= myLast) {
      // S^T = K Q^T, per key-subtile jk; C row=key=quad*4+r, col=q=l15
#pragma unroll
      for (int jk = 0; jk < 4; ++jk) {
        short8 bk0 = *(const short8*)&Ks[cur][(jk * 16 + l15) * 64 + colk0];
        short8 bk1 = *(const short8*)&Ks[cur][(jk * 16 + l15) * 64 + colk1];
        float4v s[4];
#pragma unroll
        for (int iq = 0; iq < 4; ++iq) {
          s[iq] = __builtin_amdgcn_mfma_f32_16x16x32_bf16(bk0, aq[iq][0], zero4(), 0, 0, 0);
          s[iq] = __builtin_amdgcn_mfma_f32_16x16x32_bf16(bk1, aq[iq][1], s[iq], 0, 0, 0);
        }
        if (kb == myLast) {  // only the diagonal tile needs masking
          const int key0 = kb * 64 + jk * 16 + quad * 4;
#pragma unroll
          for (int iq = 0; iq < 4; ++iq) {
            const int qg = qrow0 + iq * 16 + l15;
#pragma unroll
            for (int r = 0; r < 4; ++r)
              if (key0 + r > qg) s[iq][r] = -1e30f;
          }
        }
        // p = exp2(s) -> packed b64 (4 keys per q-row), rotated Ps layout
#pragma unroll
        for (int iq = 0; iq < 4; ++iq) {
          union { float f; uint u; } c0, c1, c2, c3;
          c0.f = exp2f(s[iq][0]); c1.f = exp2f(s[iq][1]);
          c2.f = exp2f(s[iq][2]); c3.f = exp2f(s[iq][3]);
          uint2 pk;
          pk.x = (c0.u >> 16) | (c1.u & 0xffff0000u);
          pk.y = (c2.u >> 16) | (c3.u & 0xffff0000u);
          *(uint2*)&Ps[pB + (iq * 16 + l15) * 64 + wcol[jk]] = pk;
        }
      }
      // O += P V ; l += P 1
#pragma unroll
      for (int kt2 = 0; kt2 < 2; ++kt2) {
        const int vcol = kt2 ? colk1 : colk0;
        short8 pa[4];
#pragma unroll
        for (int iq = 0; iq < 4; ++iq) {
          pa[iq] = *(const short8*)&Ps[pB + (iq * 16 + l15) * 64 + vcol];
          lacc[iq] = __builtin_amdgcn_mfma_f32_16x16x32_bf16(pa[iq], ones, lacc[iq], 0, 0, 0);
        }
#pragma unroll
        for (int jt = 0; jt < 4; ++jt) {
          short8 vb = *(const short8*)&Vts[cur][(jt * 16 + l15) * 64 + vcol];
#pragma unroll
          for (int iq = 0; iq < 4; ++iq)
            acc[iq][jt] = __builtin_amdgcn_mfma_f32_16x16x32_bf16(pa[iq], vb, acc[iq][jt], 0, 0, 0);
        }
      }
    }
    __syncthreads();  // drains prefetch glld + protects K/V buffer reuse
  }
#pragma unroll
  for (int iq = 0; iq < 4; ++iq)
#pragma unroll
    for (int r = 0; r < 4; ++r) {
      float inv = __builtin_amdgcn_rcpf(lacc[iq][r]);
      int t = qrow0 + iq * 16 + quad * 4 + r;
#pragma unroll
      for (int jt = 0; jt < 4; ++jt)
        y[(size_t)(b * 2048 + t) * 1024 + h * 64 + jt * 16 + l15] =
            f2b(acc[iq][jt][r] * inv);
    }
}

extern "C" void kernel_launch(void* const* d_in, const int* in_sizes, int n_in,
                              void* d_out, int out_size, void* d_ws, size_t ws_size,
                              hipStream_t stream) {
  const float* x       = (const float*)d_in[0];
  const float* w_attn  = (const float*)d_in[1];
  const float* b_attn  = (const float*)d_in[2];
  const float* la_attn = (const float*)d_in[3];
  const float* lb_attn = (const float*)d_in[4];
  const float* w_proj  = (const float*)d_in[5];
  const float* b_proj  = (const float*)d_in[6];
  const float* la_proj = (const float*)d_in[7];
  const float* lb_proj = (const float*)d_in[8];

  ushort* p = (ushort*)d_ws;
  ushort* xb   = p; p += (size_t)4096 * 1024;
  ushort* wab  = p; p += (size_t)3072 * 1024;
  ushort* lab  = p; p += (size_t)32 * 1024;
  ushort* lbb  = p; p += (size_t)3072 * 32;
  ushort* wpb  = p; p += (size_t)1024 * 1024;
  ushort* lpb  = p; p += (size_t)32 * 1024;
  ushort* lqb  = p; p += (size_t)1024 * 32;
  ushort* t1b  = p; p += (size_t)4096 * 32;
  ushort* t2b  = p; p += (size_t)4096 * 32;
  ushort* qkb  = p; p += (size_t)4096 * 2048;   // Q|K halves (q pre-scaled)
  ushort* vtb  = p; p += (size_t)2048 * 2048;   // V transposed [b*1024+h*64+d][t]
  ushort* yb   = p; p += (size_t)4096 * 1024;

  convert_all<<<dim3(2048), dim3(256), 0, stream>>>(
      x, w_attn, la_attn, lb_attn, w_proj, la_proj, lb_proj,
      xb, wab, lab, lbb, wpb, lpb, lqb);
  lora_t<<<dim3(512), dim3(256), 0, stream>>>(xb, lab, t1b);
  gemm_lora<false, true, 24><<<dim3(768), dim3(256), 0, stream>>>(
      xb, wab, b_attn, t1b, lbb, qkb, vtb, 1024, 2048);
  flash_attn<<<dim3(256), dim3(256), 0, stream>>>(qkb, vtb, yb);
  lora_t<<<dim3(512), dim3(256), 0, stream>>>(yb, lpb, t2b);
  gemm_lora<true, false, 8><<<dim3(256), dim3(256), 0, stream>>>(
      yb, wpb, b_proj, t2b, lqb, d_out, nullptr, 1024, 1024);
}

// Round 9
// 270.852 us; speedup vs baseline: 1.1129x; 1.1129x over previous
//
#include <hip/hip_runtime.h>
#include <hip/hip_bf16.h>

// B=2, T=2048, C=1024, H=16, HD=64, R=32, LORA_SCALE=0.5. f32 I/O, bf16 MFMA.
//   convert_all: all params+x -> bf16 ws
//   t1 = 0.5 * x @ la_attn^T                       (lora_t)
//   qk | vt = x @ w_attn^T + b_attn + t1 @ lb_attn^T  (gemm_lora; V transposed,
//             q columns pre-scaled by 0.125*log2(e) for exp2-softmax)
//   y = causal flash attention (no-max softmax, ones-MFMA row sums, S^T form)
//   t2 = 0.5 * y @ la_proj^T                       (lora_t)
//   out = y @ w_proj^T + b_proj + t2 @ lb_proj^T   (gemm_lora, f32 out)

typedef __attribute__((ext_vector_type(8))) short short8;   // 8 x bf16
typedef __attribute__((ext_vector_type(4))) float float4v;  // MFMA accum

#define QSCALE 0.18033688011112292f  // 0.125 * log2(e)

static __device__ __forceinline__ float b2f(ushort u) {
  union { uint i; float f; } v; v.i = ((uint)u) << 16; return v.f;
}
static __device__ __forceinline__ ushort f2b(float f) {
  union { float f; uint i; } v; v.f = f;
  uint i = v.i + 0x7fffu + ((v.i >> 16) & 1u);  // RNE
  return (ushort)(i >> 16);
}
static __device__ __forceinline__ float4v zero4() {
  float4v z = {0.f, 0.f, 0.f, 0.f}; return z;
}
// async global->LDS; HW dest = wave-uniform LDS base + lane*16
static __device__ __forceinline__ void glld16(const void* g, void* l) {
  __builtin_amdgcn_global_load_lds((const __attribute__((address_space(1))) void*)g,
                                   (__attribute__((address_space(3))) void*)l,
                                   16, 0, 0);
}

// ---------------- merged f32 -> bf16 conversion (7 segments, float4 chunks)
__global__ __launch_bounds__(256) void convert_all(
    const float* __restrict__ x, const float* __restrict__ wa,
    const float* __restrict__ la, const float* __restrict__ lb,
    const float* __restrict__ wp, const float* __restrict__ lp,
    const float* __restrict__ lq,
    ushort* __restrict__ xb, ushort* __restrict__ wab, ushort* __restrict__ lab,
    ushort* __restrict__ lbb, ushort* __restrict__ wpb, ushort* __restrict__ lpb,
    ushort* __restrict__ lqb) {
  const int stride = gridDim.x * blockDim.x;
  for (int i = blockIdx.x * blockDim.x + threadIdx.x; i < 2146304; i += stride) {
    const float* s; ushort* d; int off;
    if (i < 1048576)      { s = x;  d = xb;  off = i; }
    else if (i < 1835008) { s = wa; d = wab; off = i - 1048576; }
    else if (i < 1843200) { s = la; d = lab; off = i - 1835008; }
    else if (i < 1867776) { s = lb; d = lbb; off = i - 1843200; }
    else if (i < 2129920) { s = wp; d = wpb; off = i - 1867776; }
    else if (i < 2138112) { s = lp; d = lpb; off = i - 2129920; }
    else                  { s = lq; d = lqb; off = i - 2138112; }
    float4 v = ((const float4*)s)[off];
    union { ushort u[4]; uint2 p; } o;
    o.u[0] = f2b(v.x); o.u[1] = f2b(v.y); o.u[2] = f2b(v.z); o.u[3] = f2b(v.w);
    ((uint2*)d)[off] = o.p;
  }
}

// ---------------- LoRA down: T[m][r] = 0.5 * sum_k X[m][k]*La[r][k]
__global__ __launch_bounds__(256) void lora_t(
    const ushort* __restrict__ X, const ushort* __restrict__ La,
    ushort* __restrict__ T) {
  const int tid = threadIdx.x;
  const int m = blockIdx.x * 8 + (tid >> 5);
  const int r = tid & 31;
  const uint4* xr = (const uint4*)(X + (size_t)m * 1024);
  const uint4* lr = (const uint4*)(La + (size_t)r * 1024);
  float s = 0.f;
#pragma unroll 4
  for (int kk = 0; kk < 128; ++kk) {
    uint4 xv = xr[kk], lv = lr[kk];
    s += b2f((ushort)xv.x) * b2f((ushort)lv.x) + b2f((ushort)(xv.x >> 16)) * b2f((ushort)(lv.x >> 16));
    s += b2f((ushort)xv.y) * b2f((ushort)lv.y) + b2f((ushort)(xv.y >> 16)) * b2f((ushort)(lv.y >> 16));
    s += b2f((ushort)xv.z) * b2f((ushort)lv.z) + b2f((ushort)(xv.z >> 16)) * b2f((ushort)(lv.z >> 16));
    s += b2f((ushort)xv.w) * b2f((ushort)lv.w) + b2f((ushort)(xv.w >> 16)) * b2f((ushort)(lv.w >> 16));
  }
  T[(size_t)m * 32 + r] = f2b(0.5f * s);
}

// ---------------- GEMM + LoRA tail. 128x128 tile, BK=32, double-buffered LDS
// with prefetch-during-compute. XCD m-band swizzle. LoRA tail = iteration KT.
// VSPLIT: q cols (n<1024) scaled by QSCALE; v cols (n>=2048) written transposed.
template <bool OUTF32, bool VSPLIT, int NBX>
__global__ __launch_bounds__(256) void gemm_lora(
    const ushort* __restrict__ A, const ushort* __restrict__ W,
    const float* __restrict__ bias,
    const ushort* __restrict__ T1, const ushort* __restrict__ Lb,
    void* __restrict__ outv, ushort* __restrict__ vt, int K, int ldo) {
  __shared__ __attribute__((aligned(16))) ushort As[2][128 * 32];  // 8 KB each
  __shared__ __attribute__((aligned(16))) ushort Ws[2][128 * 32];
  const int tid = threadIdx.x;
  const int lane = tid & 63, wv = tid >> 6;
  const int l15 = lane & 15, quad = lane >> 4;
  const int L = blockIdx.x;
  const int x8 = L & 7, q = L >> 3;
  const int bx = q % NBX;
  const int by = x8 * 4 + q / NBX;   // nby = 32 always here
  const int m0 = by * 128, n0 = bx * 128;
  const int wm = (wv >> 1) * 64, wn = (wv & 1) * 64;
  const int r4 = lane >> 2, c4 = (lane & 3) * 8;  // 16 rows x 64B per glld16
  const int KT = K >> 5;

  float4v acc[4][4];
#pragma unroll
  for (int i = 0; i < 4; i++)
#pragma unroll
    for (int j = 0; j < 4; j++) acc[i][j] = zero4();

  auto stage = [&](int t, int buf) {
    const ushort* sA; const ushort* sW; int ld, k0;
    if (t < KT) { sA = A; sW = W; ld = K; k0 = t * 32; }
    else        { sA = T1; sW = Lb; ld = 32; k0 = 0; }
#pragma unroll
    for (int u = 0; u < 2; ++u) {
      int R = wv * 32 + u * 16;
      glld16(sA + (size_t)(m0 + R + r4) * ld + k0 + c4, &As[buf][R * 32]);
      glld16(sW + (size_t)(n0 + R + r4) * ld + k0 + c4, &Ws[buf][R * 32]);
    }
  };

  stage(0, 0);
  for (int t = 0; t <= KT; ++t) {
    __syncthreads();                     // drains stage(t) vmcnt + prev reads
    if (t < KT) stage(t + 1, (t + 1) & 1);
    const int b = t & 1;
    short8 af[4], wf[4];
#pragma unroll
    for (int i = 0; i < 4; i++)
      af[i] = *(const short8*)&As[b][(wm + i * 16 + l15) * 32 + quad * 8];
#pragma unroll
    for (int j = 0; j < 4; j++)
      wf[j] = *(const short8*)&Ws[b][(wn + j * 16 + l15) * 32 + quad * 8];
#pragma unroll
    for (int i = 0; i < 4; i++)
#pragma unroll
      for (int j = 0; j < 4; j++)
        acc[i][j] = __builtin_amdgcn_mfma_f32_16x16x32_bf16(af[i], wf[j], acc[i][j], 0, 0, 0);
  }

  const float qsc = (VSPLIT && n0 < 1024) ? QSCALE : 1.0f;
  // epilogue: C/D row = quad*4 + r, col = l15
#pragma unroll
  for (int i = 0; i < 4; i++) {
    int gm = m0 + wm + i * 16 + quad * 4;
#pragma unroll
    for (int j = 0; j < 4; j++) {
      int gn = n0 + wn + j * 16 + l15;
      float bb = bias[gn];
      if (VSPLIT && n0 >= 2048) {
        int vc = gn - 2048;                       // 0..1023 within (h,d)
        int bb2 = gm >> 11, t = gm & 2047;
        ushort u0 = f2b(acc[i][j][0] + bb), u1 = f2b(acc[i][j][1] + bb);
        ushort u2 = f2b(acc[i][j][2] + bb), u3 = f2b(acc[i][j][3] + bb);
        uint2 pk; pk.x = (uint)u0 | ((uint)u1 << 16); pk.y = (uint)u2 | ((uint)u3 << 16);
        *(uint2*)(vt + ((size_t)bb2 * 1024 + vc) * 2048 + t) = pk;
      } else {
#pragma unroll
        for (int r = 0; r < 4; r++) {
          float val = (acc[i][j][r] + bb) * qsc;
          if (OUTF32) ((float*)outv)[(size_t)(gm + r) * ldo + gn] = val;
          else        ((ushort*)outv)[(size_t)(gm + r) * ldo + gn] = f2b(val);
        }
      }
    }
  }
}

// ---------------- Causal flash attention: R7 occupancy + R8 S^T packed-P.
// grid 256 = 1 block/CU, 512 thr (8 waves = 2/SIMD — hard floor, see R8).
// Block L: bh = (L&7)*4+((L>>3)&3) (XCD-local K/V); pair g = L>>5: waves 0-3
// -> q-tile 15-g (heavy), waves 4-7 -> q-tile g (light), shared K/V staging.
// 32 q-rows/wave. S^T = K Q^T via operand-swapped MFMA (identical frag reads;
// D: row=key=quad*4+r, col=q=l15) -> P written as packed b64 (4 consecutive
// keys per q-row), loop-invariant addresses, uniform 4 dwords/bank.
// All LDS tiles col-rotated by 8*(row%8) at glld time; logical col k read at
// (k - 8*(row%8)) & 63. LDS: Ks 16KB + Vts 16KB + Ps (8 x 32x64) 32KB = 64KB.
__global__ __launch_bounds__(512) void flash_attn(
    const ushort* __restrict__ qk, const ushort* __restrict__ vt,
    ushort* __restrict__ y) {
  __shared__ __attribute__((aligned(16))) ushort Ks[2][64 * 64];
  __shared__ __attribute__((aligned(16))) ushort Vts[2][64 * 64];
  __shared__ __attribute__((aligned(16))) ushort Ps[8 * 32 * 64];
  const int tid = threadIdx.x;
  const int lane = tid & 63, wv = tid >> 6;
  const int l15 = lane & 15, quad = lane >> 4;
  const int L = blockIdx.x;
  const int bh = (L & 7) * 4 + ((L >> 3) & 3);
  const int g = L >> 5;
  const int b = bh >> 4, h = bh & 15;
  const int qbH = 15 - g, qbL = g;
  const int qtile = (wv < 4) ? qbH : qbL;
  const int wl = wv & 3;
  const int qrow0 = qtile * 128 + wl * 32;         // this wave's 32 q-rows
  const int myLast = 2 * qtile + (wl >> 1);        // last kb with unmasked keys
  const int lastH = 2 * qbH + 1;                   // block loop bound
  const ushort* qbase = qk + (size_t)b * 2048 * 2048 + h * 64;
  const ushort* kbase = qk + (size_t)b * 2048 * 2048 + 1024 + h * 64;
  const ushort* vbase = vt + ((size_t)b * 1024 + h * 64) * 2048;
  const int r8 = lane >> 3, c8 = (lane & 7) * 8;
  const int rotc = (c8 + 8 * r8) & 63;             // glld write rotation
  const int m8 = l15 & 7;
  const int colk0 = (quad * 8 + 64 - 8 * m8) & 63; // fragment read col, kt=0
  const int colk1 = (colk0 + 32) & 63;             // kt=1
  int wcol[4];                                     // P b64 write cols (per jk)
#pragma unroll
  for (int jk = 0; jk < 4; ++jk) wcol[jk] = (jk * 16 + quad * 4 + 64 - 8 * m8) & 63;
  const int pB = wv * 2048;                        // wave-private Ps (32x64)

  // stage this wave's 32 Q rows into its Ps region (rotated)
#pragma unroll
  for (int u = 0; u < 4; ++u)
    glld16(qbase + (size_t)(qrow0 + u * 8 + r8) * 2048 + rotc, &Ps[pB + u * 8 * 64]);
  // K/V tile 0 (cooperative: wave wv stages rows wv*8..+7)
  glld16(kbase + (size_t)(wv * 8 + r8) * 2048 + rotc, &Ks[0][wv * 8 * 64]);
  glld16(vbase + (size_t)(wv * 8 + r8) * 2048 + rotc, &Vts[0][wv * 8 * 64]);
  __syncthreads();
  short8 aq[2][2];
#pragma unroll
  for (int iq = 0; iq < 2; ++iq) {
    aq[iq][0] = *(const short8*)&Ps[pB + (iq * 16 + l15) * 64 + colk0];
    aq[iq][1] = *(const short8*)&Ps[pB + (iq * 16 + l15) * 64 + colk1];
  }
  // Ps region is wave-private; safe to reuse for P without a barrier.

  short8 ones;
#pragma unroll
  for (int e = 0; e < 8; e++) ones[e] = (short)0x3F80;  // bf16 1.0

  float4v acc[2][4];   // [iq][d-tile]
  float4v lacc[2];     // [iq]
#pragma unroll
  for (int i = 0; i < 2; ++i) {
    lacc[i] = zero4();
#pragma unroll
    for (int jt = 0; jt < 4; jt++) acc[i][jt] = zero4();
  }

  for (int kb = 0; kb <= lastH; ++kb) {
    const int cur = kb & 1;
    if (kb < lastH) {
      const int nb = cur ^ 1;
      glld16(kbase + (size_t)((kb + 1) * 64 + wv * 8 + r8) * 2048 + rotc,
             &Ks[nb][wv * 8 * 64]);
      glld16(vbase + (size_t)(wv * 8 + r8) * 2048 + (kb + 1) * 64 + rotc,
             &Vts[nb][wv * 8 * 64]);
    }
    if (kb <= myLast) {
      // S^T = K Q^T, per key-subtile jk; C row=key=quad*4+r, col=q=l15
#pragma unroll
      for (int jk = 0; jk < 4; ++jk) {
        short8 bk0 = *(const short8*)&Ks[cur][(jk * 16 + l15) * 64 + colk0];
        short8 bk1 = *(const short8*)&Ks[cur][(jk * 16 + l15) * 64 + colk1];
        float4v s[2];
#pragma unroll
        for (int iq = 0; iq < 2; ++iq) {
          s[iq] = __builtin_amdgcn_mfma_f32_16x16x32_bf16(bk0, aq[iq][0], zero4(), 0, 0, 0);
          s[iq] = __builtin_amdgcn_mfma_f32_16x16x32_bf16(bk1, aq[iq][1], s[iq], 0, 0, 0);
        }
        if (kb == myLast) {  // only the diagonal tile needs masking
          const int key0 = kb * 64 + jk * 16 + quad * 4;
#pragma unroll
          for (int iq = 0; iq < 2; ++iq) {
            const int qg = qrow0 + iq * 16 + l15;
#pragma unroll
            for (int r = 0; r < 4; ++r)
              if (key0 + r > qg) s[iq][r] = -1e30f;
          }
        }
        // p = exp2(s) -> packed b64 (4 keys per q-row), rotated Ps layout
#pragma unroll
        for (int iq = 0; iq < 2; ++iq) {
          union { float f; uint u; } c0, c1, c2, c3;
          c0.f = exp2f(s[iq][0]); c1.f = exp2f(s[iq][1]);
          c2.f = exp2f(s[iq][2]); c3.f = exp2f(s[iq][3]);
          uint2 pk;
          pk.x = (c0.u >> 16) | (c1.u & 0xffff0000u);
          pk.y = (c2.u >> 16) | (c3.u & 0xffff0000u);
          *(uint2*)&Ps[pB + (iq * 16 + l15) * 64 + wcol[jk]] = pk;
        }
      }
      // O += P V ; l += P 1
#pragma unroll
      for (int kt2 = 0; kt2 < 2; ++kt2) {
        const int vcol = kt2 ? colk1 : colk0;
        short8 pa[2];
#pragma unroll
        for (int iq = 0; iq < 2; ++iq) {
          pa[iq] = *(const short8*)&Ps[pB + (iq * 16 + l15) * 64 + vcol];
          lacc[iq] = __builtin_amdgcn_mfma_f32_16x16x32_bf16(pa[iq], ones, lacc[iq], 0, 0, 0);
        }
#pragma unroll
        for (int jt = 0; jt < 4; ++jt) {
          short8 vb = *(const short8*)&Vts[cur][(jt * 16 + l15) * 64 + vcol];
#pragma unroll
          for (int iq = 0; iq < 2; ++iq)
            acc[iq][jt] = __builtin_amdgcn_mfma_f32_16x16x32_bf16(pa[iq], vb, acc[iq][jt], 0, 0, 0);
        }
      }
    }
    __syncthreads();  // drains prefetch glld + protects K/V buffer reuse
  }
#pragma unroll
  for (int iq = 0; iq < 2; ++iq)
#pragma unroll
    for (int r = 0; r < 4; ++r) {
      float inv = __builtin_amdgcn_rcpf(lacc[iq][r]);
      int t = qrow0 + iq * 16 + quad * 4 + r;
#pragma unroll
      for (int jt = 0; jt < 4; ++jt)
        y[(size_t)(b * 2048 + t) * 1024 + h * 64 + jt * 16 + l15] =
            f2b(acc[iq][jt][r] * inv);
    }
}

extern "C" void kernel_launch(void* const* d_in, const int* in_sizes, int n_in,
                              void* d_out, int out_size, void* d_ws, size_t ws_size,
                              hipStream_t stream) {
  const float* x       = (const float*)d_in[0];
  const float* w_attn  = (const float*)d_in[1];
  const float* b_attn  = (const float*)d_in[2];
  const float* la_attn = (const float*)d_in[3];
  const float* lb_attn = (const float*)d_in[4];
  const float* w_proj  = (const float*)d_in[5];
  const float* b_proj  = (const float*)d_in[6];
  const float* la_proj = (const float*)d_in[7];
  const float* lb_proj = (const float*)d_in[8];

  ushort* p = (ushort*)d_ws;
  ushort* xb   = p; p += (size_t)4096 * 1024;
  ushort* wab  = p; p += (size_t)3072 * 1024;
  ushort* lab  = p; p += (size_t)32 * 1024;
  ushort* lbb  = p; p += (size_t)3072 * 32;
  ushort* wpb  = p; p += (size_t)1024 * 1024;
  ushort* lpb  = p; p += (size_t)32 * 1024;
  ushort* lqb  = p; p += (size_t)1024 * 32;
  ushort* t1b  = p; p += (size_t)4096 * 32;
  ushort* t2b  = p; p += (size_t)4096 * 32;
  ushort* qkb  = p; p += (size_t)4096 * 2048;   // Q|K halves (q pre-scaled)
  ushort* vtb  = p; p += (size_t)2048 * 2048;   // V transposed [b*1024+h*64+d][t]
  ushort* yb   = p; p += (size_t)4096 * 1024;

  convert_all<<<dim3(2048), dim3(256), 0, stream>>>(
      x, w_attn, la_attn, lb_attn, w_proj, la_proj, lb_proj,
      xb, wab, lab, lbb, wpb, lpb, lqb);
  lora_t<<<dim3(512), dim3(256), 0, stream>>>(xb, lab, t1b);
  gemm_lora<false, true, 24><<<dim3(768), dim3(256), 0, stream>>>(
      xb, wab, b_attn, t1b, lbb, qkb, vtb, 1024, 2048);
  flash_attn<<<dim3(256), dim3(512), 0, stream>>>(qkb, vtb, yb);
  lora_t<<<dim3(512), dim3(256), 0, stream>>>(yb, lpb, t2b);
  gemm_lora<true, false, 8><<<dim3(256), dim3(256), 0, stream>>>(
      yb, wpb, b_proj, t2b, lqb, d_out, nullptr, 1024, 1024);
}

// Round 10
// 258.448 us; speedup vs baseline: 1.1663x; 1.0480x over previous
//
#include <hip/hip_runtime.h>
#include <hip/hip_bf16.h>

// B=2, T=2048, C=1024, H=16, HD=64, R=32, LORA_SCALE=0.5. f32 I/O, bf16 MFMA.
//   convert_all: all params+x -> bf16 ws
//   t1 = 0.5 * x @ la_attn^T                       (lora_t)
//   qk | vt = x @ w_attn^T + b_attn + t1 @ lb_attn^T  (gemm_lora; V transposed,
//             q columns pre-scaled by 0.125*log2(e) for exp2-softmax)
//   y = causal flash attention (no-max softmax, ones-MFMA row sums, S^T form)
//   t2 = 0.5 * y @ la_proj^T                       (lora_t)
//   out = y @ w_proj^T + b_proj + t2 @ lb_proj^T   (gemm_lora, f32 out)

typedef __attribute__((ext_vector_type(8))) short short8;   // 8 x bf16
typedef __attribute__((ext_vector_type(4))) float float4v;  // MFMA accum

#define QSCALE 0.18033688011112292f  // 0.125 * log2(e)

static __device__ __forceinline__ float b2f(ushort u) {
  union { uint i; float f; } v; v.i = ((uint)u) << 16; return v.f;
}
static __device__ __forceinline__ ushort f2b(float f) {
  union { float f; uint i; } v; v.f = f;
  uint i = v.i + 0x7fffu + ((v.i >> 16) & 1u);  // RNE
  return (ushort)(i >> 16);
}
static __device__ __forceinline__ float4v zero4() {
  float4v z = {0.f, 0.f, 0.f, 0.f}; return z;
}
// async global->LDS; HW dest = wave-uniform LDS base + lane*16
static __device__ __forceinline__ void glld16(const void* g, void* l) {
  __builtin_amdgcn_global_load_lds((const __attribute__((address_space(1))) void*)g,
                                   (__attribute__((address_space(3))) void*)l,
                                   16, 0, 0);
}
// raw waitcnt: wait until <= N vm ops outstanding (expcnt/lgkmcnt ignored)
#define WAIT_VM4() __builtin_amdgcn_s_waitcnt(0xF74)
#define WAIT_VM0() __builtin_amdgcn_s_waitcnt(0xF70)

// ---------------- merged f32 -> bf16 conversion (7 segments, float4 chunks)
__global__ __launch_bounds__(256) void convert_all(
    const float* __restrict__ x, const float* __restrict__ wa,
    const float* __restrict__ la, const float* __restrict__ lb,
    const float* __restrict__ wp, const float* __restrict__ lp,
    const float* __restrict__ lq,
    ushort* __restrict__ xb, ushort* __restrict__ wab, ushort* __restrict__ lab,
    ushort* __restrict__ lbb, ushort* __restrict__ wpb, ushort* __restrict__ lpb,
    ushort* __restrict__ lqb) {
  const int stride = gridDim.x * blockDim.x;
  for (int i = blockIdx.x * blockDim.x + threadIdx.x; i < 2146304; i += stride) {
    const float* s; ushort* d; int off;
    if (i < 1048576)      { s = x;  d = xb;  off = i; }
    else if (i < 1835008) { s = wa; d = wab; off = i - 1048576; }
    else if (i < 1843200) { s = la; d = lab; off = i - 1835008; }
    else if (i < 1867776) { s = lb; d = lbb; off = i - 1843200; }
    else if (i < 2129920) { s = wp; d = wpb; off = i - 1867776; }
    else if (i < 2138112) { s = lp; d = lpb; off = i - 2129920; }
    else                  { s = lq; d = lqb; off = i - 2138112; }
    float4 v = ((const float4*)s)[off];
    union { ushort u[4]; uint2 p; } o;
    o.u[0] = f2b(v.x); o.u[1] = f2b(v.y); o.u[2] = f2b(v.z); o.u[3] = f2b(v.w);
    ((uint2*)d)[off] = o.p;
  }
}

// ---------------- LoRA down: T[m][r] = 0.5 * sum_k X[m][k]*La[r][k]
__global__ __launch_bounds__(256) void lora_t(
    const ushort* __restrict__ X, const ushort* __restrict__ La,
    ushort* __restrict__ T) {
  const int tid = threadIdx.x;
  const int m = blockIdx.x * 8 + (tid >> 5);
  const int r = tid & 31;
  const uint4* xr = (const uint4*)(X + (size_t)m * 1024);
  const uint4* lr = (const uint4*)(La + (size_t)r * 1024);
  float s = 0.f;
#pragma unroll 4
  for (int kk = 0; kk < 128; ++kk) {
    uint4 xv = xr[kk], lv = lr[kk];
    s += b2f((ushort)xv.x) * b2f((ushort)lv.x) + b2f((ushort)(xv.x >> 16)) * b2f((ushort)(lv.x >> 16));
    s += b2f((ushort)xv.y) * b2f((ushort)lv.y) + b2f((ushort)(xv.y >> 16)) * b2f((ushort)(lv.y >> 16));
    s += b2f((ushort)xv.z) * b2f((ushort)lv.z) + b2f((ushort)(xv.z >> 16)) * b2f((ushort)(lv.z >> 16));
    s += b2f((ushort)xv.w) * b2f((ushort)lv.w) + b2f((ushort)(xv.w >> 16)) * b2f((ushort)(lv.w >> 16));
  }
  T[(size_t)m * 32 + r] = f2b(0.5f * s);
}

// ---------------- GEMM + LoRA tail. 128x128 tile, BK=32, TRIPLE-buffered LDS,
// raw s_waitcnt vmcnt(4) + raw s_barrier so the iteration-t+1 prefetch stays
// in flight across the barrier (no vmcnt(0) drain). 3 buffers prevent
// stage(t+1) colliding with a wave still reading tile t-1 (one-barrier skew).
// XCD m-band swizzle. LoRA tail = iteration KT.
// VSPLIT: q cols (n<1024) scaled by QSCALE; v cols (n>=2048) written transposed.
template <bool OUTF32, bool VSPLIT, int NBX>
__global__ __launch_bounds__(256) void gemm_lora(
    const ushort* __restrict__ A, const ushort* __restrict__ W,
    const float* __restrict__ bias,
    const ushort* __restrict__ T1, const ushort* __restrict__ Lb,
    void* __restrict__ outv, ushort* __restrict__ vt, int K, int ldo) {
  __shared__ __attribute__((aligned(16))) ushort As[3][128 * 32];  // 8 KB each
  __shared__ __attribute__((aligned(16))) ushort Ws[3][128 * 32];
  const int tid = threadIdx.x;
  const int lane = tid & 63, wv = tid >> 6;
  const int l15 = lane & 15, quad = lane >> 4;
  const int L = blockIdx.x;
  const int x8 = L & 7, q = L >> 3;
  const int bx = q % NBX;
  const int by = x8 * 4 + q / NBX;   // nby = 32 always here
  const int m0 = by * 128, n0 = bx * 128;
  const int wm = (wv >> 1) * 64, wn = (wv & 1) * 64;
  const int r4 = lane >> 2, c4 = (lane & 3) * 8;  // 16 rows x 64B per glld16
  const int KT = K >> 5;

  float4v acc[4][4];
#pragma unroll
  for (int i = 0; i < 4; i++)
#pragma unroll
    for (int j = 0; j < 4; j++) acc[i][j] = zero4();

  // stage K-tile t (t==KT -> LoRA tile); 4 glld16 per wave per stage
  auto stage = [&](int t, int buf) {
    const ushort* sA; const ushort* sW; int ld, k0;
    if (t < KT) { sA = A; sW = W; ld = K; k0 = t * 32; }
    else        { sA = T1; sW = Lb; ld = 32; k0 = 0; }
#pragma unroll
    for (int u = 0; u < 2; ++u) {
      int R = wv * 32 + u * 16;
      glld16(sA + (size_t)(m0 + R + r4) * ld + k0 + c4, &As[buf][R * 32]);
      glld16(sW + (size_t)(n0 + R + r4) * ld + k0 + c4, &Ws[buf][R * 32]);
    }
  };

  stage(0, 0);
  for (int t = 0; t <= KT; ++t) {
    if (t < KT) {
      stage(t + 1, (t + 1) % 3);
      WAIT_VM4();                        // my stage(t) landed; t+1 in flight
    } else {
      WAIT_VM0();
    }
    asm volatile("" ::: "memory");
    __builtin_amdgcn_s_barrier();        // everyone's stage(t) landed
    asm volatile("" ::: "memory");
    const int b = t % 3;
    short8 af[4], wf[4];
#pragma unroll
    for (int i = 0; i < 4; i++)
      af[i] = *(const short8*)&As[b][(wm + i * 16 + l15) * 32 + quad * 8];
#pragma unroll
    for (int j = 0; j < 4; j++)
      wf[j] = *(const short8*)&Ws[b][(wn + j * 16 + l15) * 32 + quad * 8];
#pragma unroll
    for (int i = 0; i < 4; i++)
#pragma unroll
      for (int j = 0; j < 4; j++)
        acc[i][j] = __builtin_amdgcn_mfma_f32_16x16x32_bf16(af[i], wf[j], acc[i][j], 0, 0, 0);
  }

  const float qsc = (VSPLIT && n0 < 1024) ? QSCALE : 1.0f;
  // epilogue: C/D row = quad*4 + r, col = l15
#pragma unroll
  for (int i = 0; i < 4; i++) {
    int gm = m0 + wm + i * 16 + quad * 4;
#pragma unroll
    for (int j = 0; j < 4; j++) {
      int gn = n0 + wn + j * 16 + l15;
      float bb = bias[gn];
      if (VSPLIT && n0 >= 2048) {
        int vc = gn - 2048;                       // 0..1023 within (h,d)
        int bb2 = gm >> 11, t = gm & 2047;
        ushort u0 = f2b(acc[i][j][0] + bb), u1 = f2b(acc[i][j][1] + bb);
        ushort u2 = f2b(acc[i][j][2] + bb), u3 = f2b(acc[i][j][3] + bb);
        uint2 pk; pk.x = (uint)u0 | ((uint)u1 << 16); pk.y = (uint)u2 | ((uint)u3 << 16);
        *(uint2*)(vt + ((size_t)bb2 * 1024 + vc) * 2048 + t) = pk;
      } else {
#pragma unroll
        for (int r = 0; r < 4; r++) {
          float val = (acc[i][j][r] + bb) * qsc;
          if (OUTF32) ((float*)outv)[(size_t)(gm + r) * ldo + gn] = val;
          else        ((ushort*)outv)[(size_t)(gm + r) * ldo + gn] = f2b(val);
        }
      }
    }
  }
}

// ---------------- Causal flash attention: R7 occupancy + R8 S^T packed-P.
// grid 256 = 1 block/CU, 512 thr (8 waves = 2/SIMD — hard floor, see R8).
// Block L: bh = (L&7)*4+((L>>3)&3) (XCD-local K/V); pair g = L>>5: waves 0-3
// -> q-tile 15-g (heavy), waves 4-7 -> q-tile g (light), shared K/V staging.
// 32 q-rows/wave. S^T = K Q^T via operand-swapped MFMA (identical frag reads;
// D: row=key=quad*4+r, col=q=l15) -> P written as packed b64 (4 consecutive
// keys per q-row), loop-invariant addresses, uniform 4 dwords/bank.
// exp2 via raw v_exp_f32 builtin (inputs bounded; no OCML fixup VALU).
// All LDS tiles col-rotated by 8*(row%8) at glld time; logical col k read at
// (k - 8*(row%8)) & 63. LDS: Ks 16KB + Vts 16KB + Ps (8 x 32x64) 32KB = 64KB.
__global__ __launch_bounds__(512) void flash_attn(
    const ushort* __restrict__ qk, const ushort* __restrict__ vt,
    ushort* __restrict__ y) {
  __shared__ __attribute__((aligned(16))) ushort Ks[2][64 * 64];
  __shared__ __attribute__((aligned(16))) ushort Vts[2][64 * 64];
  __shared__ __attribute__((aligned(16))) ushort Ps[8 * 32 * 64];
  const int tid = threadIdx.x;
  const int lane = tid & 63, wv = tid >> 6;
  const int l15 = lane & 15, quad = lane >> 4;
  const int L = blockIdx.x;
  const int bh = (L & 7) * 4 + ((L >> 3) & 3);
  const int g = L >> 5;
  const int b = bh >> 4, h = bh & 15;
  const int qbH = 15 - g, qbL = g;
  const int qtile = (wv < 4) ? qbH : qbL;
  const int wl = wv & 3;
  const int qrow0 = qtile * 128 + wl * 32;         // this wave's 32 q-rows
  const int myLast = 2 * qtile + (wl >> 1);        // last kb with unmasked keys
  const int lastH = 2 * qbH + 1;                   // block loop bound
  const ushort* qbase = qk + (size_t)b * 2048 * 2048 + h * 64;
  const ushort* kbase = qk + (size_t)b * 2048 * 2048 + 1024 + h * 64;
  const ushort* vbase = vt + ((size_t)b * 1024 + h * 64) * 2048;
  const int r8 = lane >> 3, c8 = (lane & 7) * 8;
  const int rotc = (c8 + 8 * r8) & 63;             // glld write rotation
  const int m8 = l15 & 7;
  const int colk0 = (quad * 8 + 64 - 8 * m8) & 63; // fragment read col, kt=0
  const int colk1 = (colk0 + 32) & 63;             // kt=1
  int wcol[4];                                     // P b64 write cols (per jk)
#pragma unroll
  for (int jk = 0; jk < 4; ++jk) wcol[jk] = (jk * 16 + quad * 4 + 64 - 8 * m8) & 63;
  const int pB = wv * 2048;                        // wave-private Ps (32x64)

  // stage this wave's 32 Q rows into its Ps region (rotated)
#pragma unroll
  for (int u = 0; u < 4; ++u)
    glld16(qbase + (size_t)(qrow0 + u * 8 + r8) * 2048 + rotc, &Ps[pB + u * 8 * 64]);
  // K/V tile 0 (cooperative: wave wv stages rows wv*8..+7)
  glld16(kbase + (size_t)(wv * 8 + r8) * 2048 + rotc, &Ks[0][wv * 8 * 64]);
  glld16(vbase + (size_t)(wv * 8 + r8) * 2048 + rotc, &Vts[0][wv * 8 * 64]);
  __syncthreads();
  short8 aq[2][2];
#pragma unroll
  for (int iq = 0; iq < 2; ++iq) {
    aq[iq][0] = *(const short8*)&Ps[pB + (iq * 16 + l15) * 64 + colk0];
    aq[iq][1] = *(const short8*)&Ps[pB + (iq * 16 + l15) * 64 + colk1];
  }
  // Ps region is wave-private; safe to reuse for P without a barrier.

  short8 ones;
#pragma unroll
  for (int e = 0; e < 8; e++) ones[e] = (short)0x3F80;  // bf16 1.0

  float4v acc[2][4];   // [iq][d-tile]
  float4v lacc[2];     // [iq]
#pragma unroll
  for (int i = 0; i < 2; ++i) {
    lacc[i] = zero4();
#pragma unroll
    for (int jt = 0; jt < 4; jt++) acc[i][jt] = zero4();
  }

  for (int kb = 0; kb <= lastH; ++kb) {
    const int cur = kb & 1;
    if (kb < lastH) {
      const int nb = cur ^ 1;
      glld16(kbase + (size_t)((kb + 1) * 64 + wv * 8 + r8) * 2048 + rotc,
             &Ks[nb][wv * 8 * 64]);
      glld16(vbase + (size_t)(wv * 8 + r8) * 2048 + (kb + 1) * 64 + rotc,
             &Vts[nb][wv * 8 * 64]);
    }
    if (kb <= myLast) {
      // S^T = K Q^T, per key-subtile jk; C row=key=quad*4+r, col=q=l15
#pragma unroll
      for (int jk = 0; jk < 4; ++jk) {
        short8 bk0 = *(const short8*)&Ks[cur][(jk * 16 + l15) * 64 + colk0];
        short8 bk1 = *(const short8*)&Ks[cur][(jk * 16 + l15) * 64 + colk1];
        float4v s[2];
#pragma unroll
        for (int iq = 0; iq < 2; ++iq) {
          s[iq] = __builtin_amdgcn_mfma_f32_16x16x32_bf16(bk0, aq[iq][0], zero4(), 0, 0, 0);
          s[iq] = __builtin_amdgcn_mfma_f32_16x16x32_bf16(bk1, aq[iq][1], s[iq], 0, 0, 0);
        }
        if (kb == myLast) {  // only the diagonal tile needs masking
          const int key0 = kb * 64 + jk * 16 + quad * 4;
#pragma unroll
          for (int iq = 0; iq < 2; ++iq) {
            const int qg = qrow0 + iq * 16 + l15;
#pragma unroll
            for (int r = 0; r < 4; ++r)
              if (key0 + r > qg) s[iq][r] = -1e30f;
          }
        }
        // p = exp2(s) -> packed b64 (4 keys per q-row), rotated Ps layout
#pragma unroll
        for (int iq = 0; iq < 2; ++iq) {
          union { float f; uint u; } c0, c1, c2, c3;
          c0.f = __builtin_amdgcn_exp2f(s[iq][0]);
          c1.f = __builtin_amdgcn_exp2f(s[iq][1]);
          c2.f = __builtin_amdgcn_exp2f(s[iq][2]);
          c3.f = __builtin_amdgcn_exp2f(s[iq][3]);
          uint2 pk;
          pk.x = (c0.u >> 16) | (c1.u & 0xffff0000u);
          pk.y = (c2.u >> 16) | (c3.u & 0xffff0000u);
          *(uint2*)&Ps[pB + (iq * 16 + l15) * 64 + wcol[jk]] = pk;
        }
      }
      // O += P V ; l += P 1
#pragma unroll
      for (int kt2 = 0; kt2 < 2; ++kt2) {
        const int vcol = kt2 ? colk1 : colk0;
        short8 pa[2];
#pragma unroll
        for (int iq = 0; iq < 2; ++iq) {
          pa[iq] = *(const short8*)&Ps[pB + (iq * 16 + l15) * 64 + vcol];
          lacc[iq] = __builtin_amdgcn_mfma_f32_16x16x32_bf16(pa[iq], ones, lacc[iq], 0, 0, 0);
        }
#pragma unroll
        for (int jt = 0; jt < 4; ++jt) {
          short8 vb = *(const short8*)&Vts[cur][(jt * 16 + l15) * 64 + vcol];
#pragma unroll
          for (int iq = 0; iq < 2; ++iq)
            acc[iq][jt] = __builtin_amdgcn_mfma_f32_16x16x32_bf16(pa[iq], vb, acc[iq][jt], 0, 0, 0);
        }
      }
    }
    __syncthreads();  // drains prefetch glld + protects K/V buffer reuse
  }
#pragma unroll
  for (int iq = 0; iq < 2; ++iq)
#pragma unroll
    for (int r = 0; r < 4; ++r) {
      float inv = __builtin_amdgcn_rcpf(lacc[iq][r]);
      int t = qrow0 + iq * 16 + quad * 4 + r;
#pragma unroll
      for (int jt = 0; jt < 4; ++jt)
        y[(size_t)(b * 2048 + t) * 1024 + h * 64 + jt * 16 + l15] =
            f2b(acc[iq][jt][r] * inv);
    }
}

extern "C" void kernel_launch(void* const* d_in, const int* in_sizes, int n_in,
                              void* d_out, int out_size, void* d_ws, size_t ws_size,
                              hipStream_t stream) {
  const float* x       = (const float*)d_in[0];
  const float* w_attn  = (const float*)d_in[1];
  const float* b_attn  = (const float*)d_in[2];
  const float* la_attn = (const float*)d_in[3];
  const float* lb_attn = (const float*)d_in[4];
  const float* w_proj  = (const float*)d_in[5];
  const float* b_proj  = (const float*)d_in[6];
  const float* la_proj = (const float*)d_in[7];
  const float* lb_proj = (const float*)d_in[8];

  ushort* p = (ushort*)d_ws;
  ushort* xb   = p; p += (size_t)4096 * 1024;
  ushort* wab  = p; p += (size_t)3072 * 1024;
  ushort* lab  = p; p += (size_t)32 * 1024;
  ushort* lbb  = p; p += (size_t)3072 * 32;
  ushort* wpb  = p; p += (size_t)1024 * 1024;
  ushort* lpb  = p; p += (size_t)32 * 1024;
  ushort* lqb  = p; p += (size_t)1024 * 32;
  ushort* t1b  = p; p += (size_t)4096 * 32;
  ushort* t2b  = p; p += (size_t)4096 * 32;
  ushort* qkb  = p; p += (size_t)4096 * 2048;   // Q|K halves (q pre-scaled)
  ushort* vtb  = p; p += (size_t)2048 * 2048;   // V transposed [b*1024+h*64+d][t]
  ushort* yb   = p; p += (size_t)4096 * 1024;

  convert_all<<<dim3(2048), dim3(256), 0, stream>>>(
      x, w_attn, la_attn, lb_attn, w_proj, la_proj, lb_proj,
      xb, wab, lab, lbb, wpb, lpb, lqb);
  lora_t<<<dim3(512), dim3(256), 0, stream>>>(xb, lab, t1b);
  gemm_lora<false, true, 24><<<dim3(768), dim3(256), 0, stream>>>(
      xb, wab, b_attn, t1b, lbb, qkb, vtb, 1024, 2048);
  flash_attn<<<dim3(256), dim3(512), 0, stream>>>(qkb, vtb, yb);
  lora_t<<<dim3(512), dim3(256), 0, stream>>>(yb, lpb, t2b);
  gemm_lora<true, false, 8><<<dim3(256), dim3(256), 0, stream>>>(
      yb, wpb, b_proj, t2b, lqb, d_out, nullptr, 1024, 1024);
}